// Round 2
// baseline (115.966 us; speedup 1.0000x reference)
//
#include <hip/hip_runtime.h>

// Weighted Chamfer, B=4, N=M=8192, D=3, fp32 in/out.
// out = (1/B)*[ sum_b sum_n w*min_m d2 + sum_b sum_m min_n d2 ]
//
// MFMA formulation: one 16x16x32 bf16 MFMA produces a 16x16 tile of
// d2[n][m] = s2 + t2 - 2 s.t directly, via K-slot packing with split-bf16
// (hi+lo) error compensation:
//   k=3d+0: hs_d * (-2 ht_d);  k=3d+1: hs_d * (-2 lt_d);  k=3d+2: ls_d * (-2 ht_d)
//   k=9: h_s2*1; k=10: l_s2*1; k=11: 1*h_t2; k=12: 1*l_t2; k>=13: 0
// Dropped term ls*lt ~ 2^-18 -> d2 error ~1e-5 (threshold 5.76).
// One d2 tile feeds BOTH direction mins (fwd: per-lane running min over
// col-tiles; bwd: reg+cross-quad reduce per tile).

typedef short bf16x8 __attribute__((ext_vector_type(8)));
typedef float f32x4 __attribute__((ext_vector_type(4)));

#define BB 4
#define NP 8192
#define NFRAG (NP / 16)              // 512 fragments per batch
#define RF 8                         // row-frags per wave (128 rows)
#define WAVES 4                      // waves per block
#define ROWS_PER_BLOCK (WAVES * RF * 16)   // 512
#define RBLOCKS (NP / ROWS_PER_BLOCK)      // 16
#define CHUNKS 16                    // M chunks
#define CFRAGS (NFRAG / CHUNKS)      // 32 col-frags per chunk (512 cols)
#define CHCOLS (CFRAGS * 16)         // 512

__device__ __forceinline__ unsigned short bf16r(float x) {
    unsigned u = __float_as_uint(x);
    unsigned r = u + 0x7FFFu + ((u >> 16) & 1u);
    return (unsigned short)(r >> 16);
}
__device__ __forceinline__ float bf16f(unsigned short h) {
    return __uint_as_float(((unsigned)h) << 16);
}

// ---------- prep: build A-frag (source) and B-frag (target) matrices ----------
__global__ __launch_bounds__(256) void prep_kernel(
    const float* __restrict__ src, const float* __restrict__ tgt,
    uint4* __restrict__ afr, uint4* __restrict__ bfr, float* __restrict__ out)
{
    int gid = blockIdx.x * 256 + threadIdx.x;     // 2*4*512*64 = 262144
    if (gid == 0) out[0] = 0.0f;
    int side = gid >> 17;                          // 0 = source(A), 1 = target(B)
    int rem  = gid & 131071;
    int b    = rem >> 15;
    int f    = (rem >> 6) & (NFRAG - 1);
    int lane = rem & 63;
    int quad = lane >> 4;
    int p    = f * 16 + (lane & 15);

    const float* c = side ? tgt : src;
    size_t base = ((size_t)(b * NP + p)) * 3;
    float x = c[base + 0], y = c[base + 1], z = c[base + 2];
    float n2 = x * x + y * y + z * z;

    unsigned short hx = bf16r(x); unsigned short lx = bf16r(x - bf16f(hx));
    unsigned short hy = bf16r(y); unsigned short ly = bf16r(y - bf16f(hy));
    unsigned short hz = bf16r(z); unsigned short lz = bf16r(z - bf16f(hz));
    unsigned short h2 = bf16r(n2); unsigned short l2 = bf16r(n2 - bf16f(h2));
    const unsigned short ONE = 0x3F80;

    unsigned short v[8] = {0, 0, 0, 0, 0, 0, 0, 0};
    if (side == 0) {
        if (quad == 0) { v[0]=hx; v[1]=hx; v[2]=lx; v[3]=hy; v[4]=hy; v[5]=ly; v[6]=hz; v[7]=hz; }
        else if (quad == 1) { v[0]=lz; v[1]=h2; v[2]=l2; v[3]=ONE; v[4]=ONE; }
    } else {
        // -2*hi / -2*lo are exact bf16 (power-of-two scale)
        unsigned short nhx = bf16r(-2.f * bf16f(hx)), nlx = bf16r(-2.f * bf16f(lx));
        unsigned short nhy = bf16r(-2.f * bf16f(hy)), nly = bf16r(-2.f * bf16f(ly));
        unsigned short nhz = bf16r(-2.f * bf16f(hz)), nlz = bf16r(-2.f * bf16f(lz));
        if (quad == 0) { v[0]=nhx; v[1]=nlx; v[2]=nhx; v[3]=nhy; v[4]=nly; v[5]=nhy; v[6]=nhz; v[7]=nlz; }
        else if (quad == 1) { v[0]=nhz; v[1]=ONE; v[2]=ONE; v[3]=h2; v[4]=l2; }
    }
    uint4 pk;
    pk.x = (unsigned)v[0] | ((unsigned)v[1] << 16);
    pk.y = (unsigned)v[2] | ((unsigned)v[3] << 16);
    pk.z = (unsigned)v[4] | ((unsigned)v[5] << 16);
    pk.w = (unsigned)v[6] | ((unsigned)v[7] << 16);
    uint4* dst = side ? bfr : afr;
    dst[((size_t)b * NFRAG + f) * 64 + lane] = pk;
}

// ---------- scan: MFMA d2 tiles + dual-direction running mins ----------
__global__ __launch_bounds__(256) void scan_kernel(
    const uint4* __restrict__ afr, const uint4* __restrict__ bfr,
    float* __restrict__ fwdp, float* __restrict__ bwdp)
{
    __shared__ uint4 bsh[CFRAGS * 64];              // 32 KB: B frags of this chunk
    __shared__ float bcol[WAVES][CFRAGS][16];       // 8 KB: per-tile col mins
    const int tid  = threadIdx.x;
    const int lane = tid & 63, wave = tid >> 6;
    const int rb = blockIdx.x, b = blockIdx.y, ch = blockIdx.z;

    // stage B fragments (coalesced, conflict-free)
    const uint4* bsrc = bfr + ((size_t)b * NFRAG + ch * CFRAGS) * 64;
    for (int i = tid; i < CFRAGS * 64; i += 256) bsh[i] = bsrc[i];

    // this wave's A fragments (held in registers for the whole sweep)
    const uint4* asrc = afr + ((size_t)b * NFRAG + (rb * (WAVES * RF) + wave * RF)) * 64 + lane;
    bf16x8 afrag[RF];
#pragma unroll
    for (int r = 0; r < RF; r++) {
        uint4 t = asrc[(size_t)r * 64];
        afrag[r] = *(bf16x8*)&t;
    }
    f32x4 vmin[RF];
#pragma unroll
    for (int r = 0; r < RF; r++) { vmin[r][0]=1e30f; vmin[r][1]=1e30f; vmin[r][2]=1e30f; vmin[r][3]=1e30f; }
    f32x4 zero = {0.f, 0.f, 0.f, 0.f};
    __syncthreads();

    for (int t = 0; t < CFRAGS; t++) {
        bf16x8 bfrag = *(bf16x8*)&bsh[t * 64 + lane];
        f32x4 d[RF];
#pragma unroll
        for (int r = 0; r < RF; r++)
            d[r] = __builtin_amdgcn_mfma_f32_16x16x32_bf16(afrag[r], bfrag, zero, 0, 0, 0);
        float cm = 1e30f;
#pragma unroll
        for (int r = 0; r < RF; r++) {
            // fwd: running min over column tiles (per row, per col-residue)
            vmin[r][0] = fminf(vmin[r][0], d[r][0]);
            vmin[r][1] = fminf(vmin[r][1], d[r][1]);
            vmin[r][2] = fminf(vmin[r][2], d[r][2]);
            vmin[r][3] = fminf(vmin[r][3], d[r][3]);
            // bwd: collapse the 4 rows held in regs
            float m01 = fminf(d[r][0], d[r][1]);
            float m23 = fminf(d[r][2], d[r][3]);
            cm = fminf(cm, fminf(m01, m23));
        }
        // collapse the 4 row-quads -> per-column min over this wave's 128 rows
        cm = fminf(cm, __shfl_xor(cm, 16, 64));
        cm = fminf(cm, __shfl_xor(cm, 32, 64));
        if (lane < 16) bcol[wave][t][lane] = cm;
    }

    // fwd finalize: min across the 16 col-lanes within each quad
    const int quad = lane >> 4;
#pragma unroll
    for (int r = 0; r < RF; r++) {
#pragma unroll
        for (int e = 0; e < 4; e++) {
            float v = vmin[r][e];
            v = fminf(v, __shfl_xor(v, 8, 16));
            v = fminf(v, __shfl_xor(v, 4, 16));
            v = fminf(v, __shfl_xor(v, 2, 16));
            v = fminf(v, __shfl_xor(v, 1, 16));
            if ((lane & 15) == 0) {
                int row = (rb * (WAVES * RF) + wave * RF + r) * 16 + quad * 4 + e;
                fwdp[((size_t)b * CHUNKS + ch) * NP + row] = v;
            }
        }
    }

    // bwd: combine the 4 waves' per-tile col mins, write per-(rowblock, col)
    __syncthreads();
    for (int i = tid; i < CFRAGS * 16; i += 256) {
        int t = i >> 4, col = i & 15;
        float v = fminf(fminf(bcol[0][t][col], bcol[1][t][col]),
                        fminf(bcol[2][t][col], bcol[3][t][col]));
        int m = ch * CHCOLS + t * 16 + col;
        bwdp[((size_t)b * RBLOCKS + rb) * NP + m] = v;
    }
}

// ---------- reduce: min over partials, weight, sum, atomicAdd ----------
__global__ __launch_bounds__(256) void reduce_kernel(
    const float* __restrict__ weights, const float* __restrict__ fwdp,
    const float* __restrict__ bwdp, float* __restrict__ out)
{
    int tid = threadIdx.x;
    int gid = blockIdx.x * 256 + tid;       // 0 .. 65535
    int dir = gid >> 15;
    int r   = gid & 32767;
    int b   = r >> 13;
    int q   = r & (NP - 1);

    const float* p = dir ? (bwdp + (size_t)b * RBLOCKS * NP + q)
                         : (fwdp + (size_t)b * CHUNKS * NP + q);
    float mn = 1e30f;
#pragma unroll
    for (int i = 0; i < 16; i++) mn = fminf(mn, p[(size_t)i * NP]);
    float w = dir ? 1.0f : weights[b * NP + q];
    float v = mn * w * (1.0f / BB);
#pragma unroll
    for (int off = 32; off; off >>= 1) v += __shfl_down(v, off, 64);
    __shared__ float ls[4];
    if ((tid & 63) == 0) ls[tid >> 6] = v;
    __syncthreads();
    if (tid == 0) atomicAdd(out, ls[0] + ls[1] + ls[2] + ls[3]);
}

extern "C" void kernel_launch(void* const* d_in, const int* in_sizes, int n_in,
                              void* d_out, int out_size, void* d_ws, size_t ws_size,
                              hipStream_t stream) {
    const float* src = (const float*)d_in[0];   // (B, N, 3)
    const float* tgt = (const float*)d_in[1];   // (B, M, 3)
    const float* wgt = (const float*)d_in[2];   // (B, N)
    float* out = (float*)d_out;

    char* ws = (char*)d_ws;
    uint4* afr  = (uint4*)(ws);                                   // 2 MB
    uint4* bfr  = (uint4*)(ws + (size_t)2 * 1024 * 1024);         // 2 MB
    float* fwdp = (float*)(ws + (size_t)4 * 1024 * 1024);         // 2 MB [b][chunk][n]
    float* bwdp = (float*)(ws + (size_t)6 * 1024 * 1024);         // 2 MB [b][rb][m]

    prep_kernel<<<dim3(1024), dim3(256), 0, stream>>>(src, tgt, afr, bfr, out);
    scan_kernel<<<dim3(RBLOCKS, BB, CHUNKS), dim3(256), 0, stream>>>(afr, bfr, fwdp, bwdp);
    reduce_kernel<<<dim3(256), dim3(256), 0, stream>>>(wgt, fwdp, bwdp, out);
}

// Round 3
// 112.916 us; speedup vs baseline: 1.0270x; 1.0270x over previous
//
#include <hip/hip_runtime.h>

// Weighted Chamfer, B=4, N=M=8192, D=3, fp32 in/out.
// out = (1/B)*[ sum_b sum_n w*min_m d2 + sum_b sum_m min_n d2 ]
//
// MFMA formulation (verified round 2, absmax 0): one 16x16x32 bf16 MFMA
// yields a 16x16 tile of d2 = s2 + t2 - 2 s.t via K-slot packing with
// split-bf16 compensation. Round 3 change: the two chamfer directions are
// two SYMMETRIC row-min sweeps (dir in blockIdx.z) instead of one merged
// dual-min sweep -> no per-iteration cross-lane swizzles / LDS collapse in
// the critical path, just 8 MFMA + 32 v_min per t-iter.

typedef short bf16x8 __attribute__((ext_vector_type(8)));
typedef float f32x4 __attribute__((ext_vector_type(4)));

#define BB 4
#define NP 8192
#define NFRAG (NP / 16)              // 512 fragments per batch
#define RF 8                         // row-frags per wave (128 rows)
#define WAVES 4
#define ROWS_PER_BLOCK (WAVES * RF * 16)   // 512
#define RBLOCKS (NP / ROWS_PER_BLOCK)      // 16
#define CHUNKS 16                    // column chunks (512 cols each)
#define CFRAGS (NFRAG / CHUNKS)      // 32 col-frags per chunk

__device__ __forceinline__ unsigned short bf16r(float x) {
    unsigned u = __float_as_uint(x);
    unsigned r = u + 0x7FFFu + ((u >> 16) & 1u);
    return (unsigned short)(r >> 16);
}
__device__ __forceinline__ float bf16f(unsigned short h) {
    return __uint_as_float(((unsigned)h) << 16);
}

// ---- prep: A-frag and B-frag packs for BOTH clouds (nonzero quads only) ----
// Storage: frag f stored as 32 uint4 (lanes 0-31 = quads 0,1); quads 2,3 are
// all-zero and are materialized by scan.
__global__ __launch_bounds__(256) void prep_kernel(
    const float* __restrict__ src, const float* __restrict__ tgt,
    uint4* __restrict__ aS, uint4* __restrict__ bS,
    uint4* __restrict__ aT, uint4* __restrict__ bT,
    float* __restrict__ out)
{
    int gid = blockIdx.x * 256 + threadIdx.x;   // 2*4*512*32 = 131072
    if (gid == 0) out[0] = 0.0f;
    int cloud = gid >> 16;                      // 0 = source, 1 = target
    int rem   = gid & 65535;
    int b     = rem >> 14;
    int f     = (rem >> 5) & (NFRAG - 1);
    int lane  = rem & 31;
    int quad  = lane >> 4;                      // 0 or 1
    int p     = f * 16 + (lane & 15);

    const float* c = cloud ? tgt : src;
    size_t base = ((size_t)b * NP + p) * 3;
    float x = c[base + 0], y = c[base + 1], z = c[base + 2];
    float n2 = x * x + y * y + z * z;

    unsigned short hx = bf16r(x), lx = bf16r(x - bf16f(hx));
    unsigned short hy = bf16r(y), ly = bf16r(y - bf16f(hy));
    unsigned short hz = bf16r(z), lz = bf16r(z - bf16f(hz));
    unsigned short h2 = bf16r(n2), l2 = bf16r(n2 - bf16f(h2));
    // -2*hi / -2*lo exact (power-of-two scale)
    unsigned short nhx = bf16r(-2.f * bf16f(hx)), nlx = bf16r(-2.f * bf16f(lx));
    unsigned short nhy = bf16r(-2.f * bf16f(hy)), nly = bf16r(-2.f * bf16f(ly));
    unsigned short nhz = bf16r(-2.f * bf16f(hz)), nlz = bf16r(-2.f * bf16f(lz));
    const unsigned short ONE = 0x3F80;

    unsigned short va[8] = {0,0,0,0,0,0,0,0};
    unsigned short vb[8] = {0,0,0,0,0,0,0,0};
    if (quad == 0) {
        va[0]=hx; va[1]=hx; va[2]=lx; va[3]=hy; va[4]=hy; va[5]=ly; va[6]=hz; va[7]=hz;
        vb[0]=nhx; vb[1]=nlx; vb[2]=nhx; vb[3]=nhy; vb[4]=nly; vb[5]=nhy; vb[6]=nhz; vb[7]=nlz;
    } else {
        va[0]=lz; va[1]=h2; va[2]=l2; va[3]=ONE; va[4]=ONE;
        vb[0]=nhz; vb[1]=ONE; vb[2]=ONE; vb[3]=h2; vb[4]=l2;
    }
    uint4 pa, pb;
    pa.x = (unsigned)va[0] | ((unsigned)va[1] << 16);
    pa.y = (unsigned)va[2] | ((unsigned)va[3] << 16);
    pa.z = (unsigned)va[4] | ((unsigned)va[5] << 16);
    pa.w = (unsigned)va[6] | ((unsigned)va[7] << 16);
    pb.x = (unsigned)vb[0] | ((unsigned)vb[1] << 16);
    pb.y = (unsigned)vb[2] | ((unsigned)vb[3] << 16);
    pb.z = (unsigned)vb[4] | ((unsigned)vb[5] << 16);
    pb.w = (unsigned)vb[6] | ((unsigned)vb[7] << 16);
    size_t off = ((size_t)b * NFRAG + f) * 32 + lane;
    (cloud ? aT : aS)[off] = pa;
    (cloud ? bT : bS)[off] = pb;
}

// ---- scan: one direction per block; per-row running mins, no per-iter shuffles ----
__global__ __launch_bounds__(256) void scan_kernel(
    const uint4* __restrict__ aS, const uint4* __restrict__ bS,
    const uint4* __restrict__ aT, const uint4* __restrict__ bT,
    float* __restrict__ part)   // part[dir][b][ch][row]
{
    __shared__ uint4 bsh[CFRAGS * 64];          // 32 KB
    const int tid = threadIdx.x;
    const int lane = tid & 63, wave = tid >> 6;
    const int rb = blockIdx.x, b = blockIdx.y;
    const int dir = blockIdx.z >> 4, ch = blockIdx.z & (CHUNKS - 1);

    // dir 0: rows = source, cols = target. dir 1: rows = target, cols = source.
    const uint4* afr = dir ? aT : aS;
    const uint4* bfr = dir ? bS : bT;
    const uint4 z4 = make_uint4(0u, 0u, 0u, 0u);

    // stage B frags, materializing the zero quads (lanes 32-63)
    const uint4* bsrc = bfr + ((size_t)b * NFRAG + ch * CFRAGS) * 32;
    for (int i = tid; i < CFRAGS * 64; i += 256) {
        int f = i >> 6, l = i & 63;
        bsh[i] = (l < 32) ? bsrc[f * 32 + l] : z4;
    }

    // this wave's A frags (registers for the whole sweep)
    const uint4* asrc = afr + ((size_t)b * NFRAG + rb * (WAVES * RF) + wave * RF) * 32;
    bf16x8 afrag[RF];
#pragma unroll
    for (int r = 0; r < RF; r++) {
        uint4 t = (lane < 32) ? asrc[r * 32 + lane] : z4;
        afrag[r] = *(bf16x8*)&t;
    }
    f32x4 vmin[RF];
#pragma unroll
    for (int r = 0; r < RF; r++) { vmin[r][0]=1e30f; vmin[r][1]=1e30f; vmin[r][2]=1e30f; vmin[r][3]=1e30f; }
    f32x4 zero = {0.f, 0.f, 0.f, 0.f};
    __syncthreads();

#pragma unroll 2
    for (int t = 0; t < CFRAGS; t++) {
        bf16x8 bfrag = *(bf16x8*)&bsh[t * 64 + lane];
#pragma unroll
        for (int r = 0; r < RF; r++) {
            f32x4 d = __builtin_amdgcn_mfma_f32_16x16x32_bf16(afrag[r], bfrag, zero, 0, 0, 0);
            vmin[r][0] = fminf(vmin[r][0], d[0]);
            vmin[r][1] = fminf(vmin[r][1], d[1]);
            vmin[r][2] = fminf(vmin[r][2], d[2]);
            vmin[r][3] = fminf(vmin[r][3], d[3]);
        }
    }

    // finalize: min across the 16 col-lanes within each quad (once per block)
    const int quad = lane >> 4;
#pragma unroll
    for (int r = 0; r < RF; r++) {
#pragma unroll
        for (int e = 0; e < 4; e++) {
            float v = vmin[r][e];
            v = fminf(v, __shfl_xor(v, 8, 16));
            v = fminf(v, __shfl_xor(v, 4, 16));
            v = fminf(v, __shfl_xor(v, 2, 16));
            v = fminf(v, __shfl_xor(v, 1, 16));
            if ((lane & 15) == 0) {
                int row = (rb * (WAVES * RF) + wave * RF + r) * 16 + quad * 4 + e;
                part[((size_t)(dir * BB + b) * CHUNKS + ch) * NP + row] = v;
            }
        }
    }
}

// ---- reduce: min over chunks, weight, sum, atomicAdd ----
__global__ __launch_bounds__(256) void reduce_kernel(
    const float* __restrict__ weights, const float* __restrict__ part,
    float* __restrict__ out)
{
    int tid = threadIdx.x;
    int gid = blockIdx.x * 256 + tid;       // 0 .. 65535
    int dir = gid >> 15;
    int r   = gid & 32767;
    int b   = r >> 13;
    int q   = r & (NP - 1);

    const float* p = part + ((size_t)(dir * BB + b) * CHUNKS) * NP + q;
    float mn = 1e30f;
#pragma unroll
    for (int i = 0; i < CHUNKS; i++) mn = fminf(mn, p[(size_t)i * NP]);
    float w = dir ? 1.0f : weights[b * NP + q];
    float v = mn * w * (1.0f / BB);
#pragma unroll
    for (int off = 32; off; off >>= 1) v += __shfl_down(v, off, 64);
    __shared__ float ls[4];
    if ((tid & 63) == 0) ls[tid >> 6] = v;
    __syncthreads();
    if (tid == 0) atomicAdd(out, ls[0] + ls[1] + ls[2] + ls[3]);
}

extern "C" void kernel_launch(void* const* d_in, const int* in_sizes, int n_in,
                              void* d_out, int out_size, void* d_ws, size_t ws_size,
                              hipStream_t stream) {
    const float* src = (const float*)d_in[0];   // (B, N, 3)
    const float* tgt = (const float*)d_in[1];   // (B, M, 3)
    const float* wgt = (const float*)d_in[2];   // (B, N)
    float* out = (float*)d_out;

    // frag matrices: 4 * (4b * 512f * 32 lanes * 16B) = 4 MB; partials 4 MB.
    char* ws = (char*)d_ws;
    const size_t FRAG_BYTES = (size_t)BB * NFRAG * 32 * 16;   // 1 MB each
    uint4* aS = (uint4*)(ws + 0 * FRAG_BYTES);
    uint4* bS = (uint4*)(ws + 1 * FRAG_BYTES);
    uint4* aT = (uint4*)(ws + 2 * FRAG_BYTES);
    uint4* bT = (uint4*)(ws + 3 * FRAG_BYTES);
    float* part = (float*)(ws + 4 * FRAG_BYTES);              // 4 MB

    prep_kernel<<<dim3(512), dim3(256), 0, stream>>>(src, tgt, aS, bS, aT, bT, out);
    scan_kernel<<<dim3(RBLOCKS, BB, 2 * CHUNKS), dim3(256), 0, stream>>>(aS, bS, aT, bT, part);
    reduce_kernel<<<dim3(256), dim3(256), 0, stream>>>(wgt, part, out);
}

// Round 4
// 88.787 us; speedup vs baseline: 1.3061x; 1.2718x over previous
//
#include <hip/hip_runtime.h>

// Weighted Chamfer, B=4, N=M=8192, D=3, fp32 in/out.
// out = (1/B)*[ sum_b sum_n w*min_m d2 + sum_b sum_m min_n d2 ]
//
// One v_mfma_f32_32x32x16_bf16 yields a 32x32 tile of d2 = s2 + t2 - 2 s.t
// via K-slot packing with split-bf16 compensation (verified round 2/3):
//   k0-8: {hs,hs,ls}x * {-2ht,-2lt,-2ht}x per dim; k9-10: {h,l}(s2)*1;
//   k11-12: 1*{h,l}(t2); k13-15: zero.  Error ~1e-5 (threshold 5.76).
// A-operand layout: A[m=lane&31][k=(lane>>5)*8+j]; B symmetric.
// C/D layout (m74/m101): col=lane&31, row=(reg&3)+8*(reg>>2)+4*(lane>>5).
//
// Round 4: __launch_bounds__(256,4) so accumulators stay in arch VGPRs
// (round 3's VGPR_Count=56 showed AGPR-split -> 3.8x VALU inflation);
// 32x32 shape (4x fewer MFMA/ds_read/iters); min3 pairing (0.5 vmin/value).

typedef short bf16x8 __attribute__((ext_vector_type(8)));
typedef float f32x16 __attribute__((ext_vector_type(16)));

#define BB 4
#define NP 8192
#define NFRAG (NP / 32)          // 256 32-row fragments per batch
#define RF 2                     // row-frags per wave (64 rows)
#define WAVES 4                  // 256 rows per block
#define RBLOCKS 32               // 8192 / 256
#define CFRAGS 32                // frags per LDS stage (1024 cols, 32 KB)
#define CG 2                     // stages per block -> 2048 cols
#define NCHG 4                   // column groups (8192 / 2048)

__device__ __forceinline__ unsigned short bf16r(float x) {
    unsigned u = __float_as_uint(x);
    unsigned r = u + 0x7FFFu + ((u >> 16) & 1u);
    return (unsigned short)(r >> 16);
}
__device__ __forceinline__ float bf16f(unsigned short h) {
    return __uint_as_float(((unsigned)h) << 16);
}

// ---- prep: A-pack and B-pack (32x32x16 fragment layout) for both clouds ----
__global__ __launch_bounds__(256) void prep_kernel(
    const float* __restrict__ src, const float* __restrict__ tgt,
    uint4* __restrict__ aS, uint4* __restrict__ bS,
    uint4* __restrict__ aT, uint4* __restrict__ bT,
    float* __restrict__ out)
{
    int gid = blockIdx.x * 256 + threadIdx.x;   // 2*4*256*64 = 131072
    if (gid == 0) out[0] = 0.0f;
    int cloud = gid >> 16;
    int rem   = gid & 65535;
    int b     = rem >> 14;
    int f     = (rem >> 6) & (NFRAG - 1);
    int lane  = rem & 63;
    int half  = lane >> 5;
    int p     = f * 32 + (lane & 31);

    const float* c = cloud ? tgt : src;
    size_t base = ((size_t)b * NP + p) * 3;
    float x = c[base + 0], y = c[base + 1], z = c[base + 2];
    float n2 = x * x + y * y + z * z;

    unsigned short hx = bf16r(x), lx = bf16r(x - bf16f(hx));
    unsigned short hy = bf16r(y), ly = bf16r(y - bf16f(hy));
    unsigned short hz = bf16r(z), lz = bf16r(z - bf16f(hz));
    unsigned short h2 = bf16r(n2), l2 = bf16r(n2 - bf16f(h2));
    unsigned short nhx = bf16r(-2.f * bf16f(hx)), nlx = bf16r(-2.f * bf16f(lx));
    unsigned short nhy = bf16r(-2.f * bf16f(hy)), nly = bf16r(-2.f * bf16f(ly));
    unsigned short nhz = bf16r(-2.f * bf16f(hz)), nlz = bf16r(-2.f * bf16f(lz));
    const unsigned ONE = 0x3F80u;

    uint4 pa, pb;
    if (half == 0) {   // k = 0..7
        pa.x = (unsigned)hx | ((unsigned)hx << 16);
        pa.y = (unsigned)lx | ((unsigned)hy << 16);
        pa.z = (unsigned)hy | ((unsigned)ly << 16);
        pa.w = (unsigned)hz | ((unsigned)hz << 16);
        pb.x = (unsigned)nhx | ((unsigned)nlx << 16);
        pb.y = (unsigned)nhx | ((unsigned)nhy << 16);
        pb.z = (unsigned)nly | ((unsigned)nhy << 16);
        pb.w = (unsigned)nhz | ((unsigned)nlz << 16);
    } else {           // k = 8..15 (13..15 zero)
        pa.x = (unsigned)lz | ((unsigned)h2 << 16);
        pa.y = (unsigned)l2 | (ONE << 16);
        pa.z = ONE;
        pa.w = 0u;
        pb.x = (unsigned)nhz | (ONE << 16);
        pb.y = ONE | ((unsigned)h2 << 16);
        pb.z = (unsigned)l2;
        pb.w = 0u;
    }
    size_t off = ((size_t)b * NFRAG + f) * 64 + lane;
    (cloud ? aT : aS)[off] = pa;
    (cloud ? bT : bS)[off] = pb;
}

// ---- scan: one direction per block; 32x32 MFMA + paired min3 accumulation ----
__global__ __launch_bounds__(256, 4) void scan_kernel(
    const uint4* __restrict__ aS, const uint4* __restrict__ bS,
    const uint4* __restrict__ aT, const uint4* __restrict__ bT,
    float* __restrict__ part)   // part[dir][b][cg][row]
{
    __shared__ uint4 bsh[CFRAGS * 64];          // 32 KB
    const int tid = threadIdx.x;
    const int lane = tid & 63, wave = tid >> 6;
    const int rb = blockIdx.x, b = blockIdx.y;
    const int dir = blockIdx.z >> 2, cg = blockIdx.z & (NCHG - 1);

    const uint4* afr = dir ? aT : aS;   // rows = queries
    const uint4* bfr = dir ? bS : bT;   // cols = database

    // this wave's A frags (registers for the whole sweep)
    const uint4* asrc = afr + ((size_t)b * NFRAG + rb * (WAVES * RF) + wave * RF) * 64 + lane;
    bf16x8 afrag[RF];
#pragma unroll
    for (int r = 0; r < RF; r++) {
        uint4 t = asrc[r * 64];
        afrag[r] = *(bf16x8*)&t;
    }
    f32x16 vmin[RF];
#pragma unroll
    for (int r = 0; r < RF; r++)
#pragma unroll
        for (int i = 0; i < 16; i++) vmin[r][i] = 1e30f;
    f32x16 zero = {};

    for (int cgi = 0; cgi < CG; cgi++) {
        if (cgi) __syncthreads();
        const uint4* bsrc = bfr + ((size_t)b * NFRAG + (cg * CG + cgi) * CFRAGS) * 64;
        for (int i = tid; i < CFRAGS * 64; i += 256) bsh[i] = bsrc[i];
        __syncthreads();

        for (int t = 0; t < CFRAGS; t += 2) {
            bf16x8 b0 = *(bf16x8*)&bsh[t * 64 + lane];
            bf16x8 b1 = *(bf16x8*)&bsh[(t + 1) * 64 + lane];
#pragma unroll
            for (int r = 0; r < RF; r++) {
                f32x16 dA = __builtin_amdgcn_mfma_f32_32x32x16_bf16(afrag[r], b0, zero, 0, 0, 0);
                f32x16 dB = __builtin_amdgcn_mfma_f32_32x32x16_bf16(afrag[r], b1, zero, 0, 0, 0);
#pragma unroll
                for (int i = 0; i < 16; i++)
                    vmin[r][i] = fminf(fminf(dA[i], dB[i]), vmin[r][i]);  // v_min3_f32
            }
        }
    }

    // finalize: min across the 32 col-lanes (xor bits 0-4 stay within half)
    const int half = lane >> 5;
#pragma unroll
    for (int r = 0; r < RF; r++) {
#pragma unroll
        for (int i = 0; i < 16; i++) {
            float v = vmin[r][i];
            v = fminf(v, __shfl_xor(v, 16, 64));
            v = fminf(v, __shfl_xor(v, 8, 64));
            v = fminf(v, __shfl_xor(v, 4, 64));
            v = fminf(v, __shfl_xor(v, 2, 64));
            v = fminf(v, __shfl_xor(v, 1, 64));
            if ((lane & 31) == 0) {
                int row = rb * (WAVES * RF * 32) + (wave * RF + r) * 32
                        + (i & 3) + 8 * (i >> 2) + 4 * half;
                part[((size_t)(dir * BB + b) * NCHG + cg) * NP + row] = v;
            }
        }
    }
}

// ---- reduce: min over column groups, weight, sum, atomicAdd ----
__global__ __launch_bounds__(256) void reduce_kernel(
    const float* __restrict__ weights, const float* __restrict__ part,
    float* __restrict__ out)
{
    int tid = threadIdx.x;
    int gid = blockIdx.x * 256 + tid;       // 0 .. 65535
    int dir = gid >> 15;
    int r   = gid & 32767;
    int b   = r >> 13;
    int q   = r & (NP - 1);

    const float* p = part + ((size_t)(dir * BB + b) * NCHG) * NP + q;
    float mn = 1e30f;
#pragma unroll
    for (int i = 0; i < NCHG; i++) mn = fminf(mn, p[(size_t)i * NP]);
    float w = dir ? 1.0f : weights[b * NP + q];
    float v = mn * w * (1.0f / BB);
#pragma unroll
    for (int off = 32; off; off >>= 1) v += __shfl_down(v, off, 64);
    __shared__ float ls[4];
    if ((tid & 63) == 0) ls[tid >> 6] = v;
    __syncthreads();
    if (tid == 0) atomicAdd(out, ls[0] + ls[1] + ls[2] + ls[3]);
}

extern "C" void kernel_launch(void* const* d_in, const int* in_sizes, int n_in,
                              void* d_out, int out_size, void* d_ws, size_t ws_size,
                              hipStream_t stream) {
    const float* src = (const float*)d_in[0];   // (B, N, 3)
    const float* tgt = (const float*)d_in[1];   // (B, M, 3)
    const float* wgt = (const float*)d_in[2];   // (B, N)
    float* out = (float*)d_out;

    char* ws = (char*)d_ws;
    const size_t FRAG_BYTES = (size_t)BB * NFRAG * 64 * 16;   // 1 MB each
    uint4* aS = (uint4*)(ws + 0 * FRAG_BYTES);
    uint4* bS = (uint4*)(ws + 1 * FRAG_BYTES);
    uint4* aT = (uint4*)(ws + 2 * FRAG_BYTES);
    uint4* bT = (uint4*)(ws + 3 * FRAG_BYTES);
    float* part = (float*)(ws + 4 * FRAG_BYTES);              // 1 MB

    prep_kernel<<<dim3(512), dim3(256), 0, stream>>>(src, tgt, aS, bS, aT, bT, out);
    scan_kernel<<<dim3(RBLOCKS, BB, 2 * NCHG), dim3(256), 0, stream>>>(aS, bS, aT, bT, part);
    reduce_kernel<<<dim3(256), dim3(256), 0, stream>>>(wgt, part, out);
}